// Round 13
// baseline (206.931 us; speedup 1.0000x reference)
//
#include <hip/hip_runtime.h>

// B=8, C=64, D=8 (q/k), H=W=128.  dwconv3x3 -> CCA -> CCA -> pointwise.
// Round 18 = r17 pixel-major design with the staging-count bug fixed:
// the three pixel-major plane loops (ccdir mode1 staging, yR2 copy, pw
// staging) covered only 512 of 1024 uint4 chunks (pixels 0-63) -> NaN.
// Now k<4 (4 chunks/thread).  Design recap:
//   - intermediates pixel-major R2(b,h,w,c), 128B/pixel;
//   - ccdir un-swapped PV -> lane holds 4 consecutive d -> direct
//     pixel-major OW (contiguous plane) / OH (128B @8KB) writes;
//   - comb = pure streaming elementwise (no LDS), fill-like pattern;
//   - cc pass1 + pw stage contiguous 16KB planes (2 loads+writes x4).
// Fragment layouts (mfma_f32_16x16x32_bf16):
//   A[m=lane&15][k=quad*8+j (+32s)], B[k][n=lane&15], C col=lane&15,row=quad*4+reg
// (mfma_f32_16x16x16bf16_1k): A[m=lane&15][k=quad*4+j], B[k=quad*4+j][n=lane&15],
//   C col=lane&15,row=quad*4+reg.

#define NEGINF -3.0e38f

typedef __attribute__((ext_vector_type(8))) __bf16 bf8;
typedef __attribute__((ext_vector_type(4))) __bf16 bf4;
typedef __attribute__((ext_vector_type(4))) short s4;
typedef __attribute__((ext_vector_type(4))) float f4;

__device__ __forceinline__ f4 MFMA(bf8 a, bf8 b, f4 c) {
  return __builtin_amdgcn_mfma_f32_16x16x32_bf16(a, b, c, 0, 0, 0);
}
__device__ __forceinline__ f4 MFMA16(bf4 a, bf4 b, f4 c) {
  return __builtin_amdgcn_mfma_f32_16x16x16bf16_1k(*(s4*)&a, *(s4*)&b, c, 0, 0, 0);
}
__device__ __forceinline__ ushort bfb(float f) {
  __bf16 h = (__bf16)f;
  return *(ushort*)&h;
}
__device__ __forceinline__ float b2f(ushort u) {
  return (float)*(__bf16*)&u;
}

// 32x32-tile dwconv3x3; writes y_cp and yT_cp (channel-plane bf16).
// Block (0,0,0) lanes 0-63 also pack the weight-fragment tables.
__global__ __launch_bounds__(256) void dwconv_kernel(
    const float* __restrict__ x, const float* __restrict__ wdw,
    __bf16* __restrict__ y, __bf16* __restrict__ yT,
    const float* __restrict__ wq, const float* __restrict__ wk,
    const float* __restrict__ wv, const float* __restrict__ wpw,
    __bf16* __restrict__ wtab, __bf16* __restrict__ ptab) {
  __shared__ float in[34][36];
  __shared__ float ot[32][33];
  if (blockIdx.x == 0 && blockIdx.y == 0 && blockIdx.z == 0 &&
      threadIdx.x < 64) {
    int lane = threadIdx.x;
    int l16 = lane & 15, quad = lane >> 4;
    const float* wr = (l16 < 8) ? (wq + l16*64) : (wk + (l16 - 8)*64);
    float scale = (l16 < 8) ? 1.4426950408889634f : 1.0f;   // log2(e) on wq
    for (int s = 0; s < 2; ++s)
      for (int j = 0; j < 8; ++j)
        wtab[(s*64 + lane)*8 + j] = (__bf16)(wr[quad*8 + s*32 + j]*scale);
    for (int m0 = 0; m0 < 4; ++m0) {
      const float* vr = wv + (m0*16 + l16)*64;
      const float* pr = wpw + (m0*16 + l16)*64;
      for (int s = 0; s < 2; ++s)
        for (int j = 0; j < 8; ++j) {
          wtab[((2 + m0*2 + s)*64 + lane)*8 + j] = (__bf16)vr[quad*8 + s*32 + j];
          ptab[((m0*2 + s)*64 + lane)*8 + j]     = (__bf16)pr[quad*8 + s*32 + j];
        }
    }
  }
  int tx = threadIdx.x & 31, ty = threadIdx.x >> 5;   // 32x8
  int w0 = blockIdx.x*32, h0 = blockIdx.y*32;
  int n = blockIdx.z;                                  // b*64 + c
  const float* xp = x + (size_t)n*16384;
  const float* wp = wdw + (n & 63)*9;
  float wr[9];
  #pragma unroll
  for (int j = 0; j < 9; ++j) wr[j] = wp[j];
  for (int idx = threadIdx.x; idx < 1156; idx += 256) {  // 34*34 linear
    int i = idx/34, j = idx - i*34;
    int hh = h0 + i - 1, ww = w0 + j - 1;
    float v = 0.f;
    if (hh >= 0 && hh < 128 && ww >= 0 && ww < 128) v = xp[hh*128 + ww];
    in[i][j] = v;
  }
  __syncthreads();
  for (int i2 = ty; i2 < 32; i2 += 8) {
    float acc = 0.f;
    #pragma unroll
    for (int kh = 0; kh < 3; ++kh)
      #pragma unroll
      for (int kw = 0; kw < 3; ++kw)
        acc += wr[kh*3 + kw]*in[i2 + kh][tx + kw];
    ot[i2][tx] = acc;
  }
  __syncthreads();
  ushort* yp  = (ushort*)(y  + (size_t)n*16384);
  ushort* ytp = (ushort*)(yT + (size_t)n*16384);
  for (int idx = threadIdx.x; idx < 512; idx += 256) {
    int row = idx >> 4, c2 = (idx & 15)*2;
    ushort2 u;
    u.x = bfb(ot[row][c2]); u.y = bfb(ot[row][c2 + 1]);
    *(ushort2*)&yp[(size_t)(h0 + row)*128 + w0 + c2] = u;
    ushort2 v;
    v.x = bfb(ot[c2][row]); v.y = bfb(ot[c2 + 1][row]);
    *(ushort2*)&ytp[(size_t)(w0 + row)*128 + h0 + c2] = v;
  }
}

// Fused CCA direction kernel.  Outputs UNNORMALIZED, PIXEL-MAJOR:
//   dir0 (row r):  OW(b, r, w=p, d) -- contiguous 16KB plane.
//   dir1 (col r):  OH(b, h=p, r, d) -- 128B chunk per pixel @ 8KB stride.
// mode0: stage from channel-planes srcA(row)/srcB(col) [r14 path]; dir0
//   also copies the staged plane to yR2 (pixel-major residual for comb0).
// mode1: stage from pixel-major srcA rows (dir0, contiguous) / cols (dir1).
// LDS time-share: region A @0 (18432) = ys[128][72] -> vs[64][140] ->
// per-wave out-stage [32][70]; ks @18432 (2048).
__global__ __launch_bounds__(256) void ccdir_kernel(
    const ushort* __restrict__ srcA, const ushort* __restrict__ srcB,
    ushort* __restrict__ OW, ushort* __restrict__ OH,
    ushort* __restrict__ yR2,
    const __bf16* __restrict__ wtab,
    float* __restrict__ sW, float* __restrict__ sH, int mode) {
  __shared__ __align__(16) char smem[20480];
  __bf16* ys = (__bf16*)smem;
  __bf16* vs = (__bf16*)smem;                 // alias (post-B0b)
  __bf16* ks = (__bf16*)(smem + 18432);

  int t = threadIdx.x;
  int r = blockIdx.x, b = blockIdx.y, dir = blockIdx.z;
  float* so = dir ? sH : sW;

  int lane = t & 63, w = t >> 6;
  int l16 = lane & 15, quad = lane >> 4;

  // ---- stage Y[c][p] -> ys[p][c-chunk-swizzled] ----
  if (mode == 0) {
    const ushort* sp = (dir ? srcB : srcA) + (size_t)b*1048576 + (size_t)r*128;
    int a = t & 15, cp = t >> 4;
    ushort* yr = (ushort*)ys;
    #pragma unroll
    for (int q = 0; q < 2; ++q) {
      int c = 2*cp + 32*q;
      uint4 u0 = *(const uint4*)&sp[(size_t)c*16384 + a*8];
      uint4 u1 = *(const uint4*)&sp[(size_t)(c + 1)*16384 + a*8];
      const ushort* p0 = (const ushort*)&u0;
      const ushort* p1 = (const ushort*)&u1;
      int cx = (((c >> 3) ^ a) & 7)*8 + (c & 7);
      #pragma unroll
      for (int j = 0; j < 8; ++j) {
        ushort2 uv; uv.x = p0[j]; uv.y = p1[j];
        *(ushort2*)&yr[(a*8 + j)*72 + cx] = uv;
      }
    }
  } else {
    const ushort* base = dir ? (srcA + (size_t)b*1048576 + (size_t)r*64)
                             : (srcA + ((size_t)b*128 + r)*8192);
    #pragma unroll
    for (int k = 0; k < 4; ++k) {              // 1024 chunks = full plane
      int i = t + 256*k;
      int p = i >> 3, c0 = (i & 7)*8;
      size_t off = dir ? ((size_t)p*8192 + c0) : ((size_t)p*64 + c0);
      uint4 u = *(const uint4*)&base[off];
      int cx = ((c0 >> 3) ^ (p >> 3)) & 7;
      *(uint4*)((ushort*)ys + p*72 + cx*8) = u;
    }
  }
  bf8 a_qk[2];
  #pragma unroll
  for (int s = 0; s < 2; ++s)
    a_qk[s] = *(const bf8*)&wtab[(s*64 + lane)*8];
  __syncthreads();                      // B0: ys staged

  // ---- frag loads (+ pixel-major y copy in mode0/dir0) + QK proj ----
  f4 z4 = {0.f, 0.f, 0.f, 0.f};
  bf4 zb4;
  #pragma unroll
  for (int j = 0; j < 4; ++j) zb4[j] = (__bf16)0.f;
  bf8 b_ys[2][2];
  #pragma unroll
  for (int nt = 0; nt < 2; ++nt) {
    int p = w*32 + nt*16 + l16;
    int hi = (p >> 3) & 7;
    #pragma unroll
    for (int s = 0; s < 2; ++s)
      b_ys[nt][s] = *(const bf8*)&ys[p*72 + ((s*4 + quad) ^ hi)*8];
  }
  if (mode == 0 && dir == 0) {          // residual copy y -> yR2 (16KB plane)
    ushort* yp = yR2 + ((size_t)b*128 + r)*8192;
    #pragma unroll
    for (int k = 0; k < 4; ++k) {              // full plane
      int i = t + 256*k;
      int pp = i >> 3, c0 = (i & 7)*8;
      int cx = ((c0 >> 3) ^ (pp >> 3)) & 7;
      uint4 v = *(const uint4*)((ushort*)ys + pp*72 + cx*8);
      *(uint4*)&yp[(size_t)pp*64 + c0] = v;
    }
  }
  // QK proj: C rows 0-7 = Q (quads 0,1) stay in regs; rows 8-15 = K -> ks.
  bf4 bq[2];
  #pragma unroll
  for (int nt = 0; nt < 2; ++nt) {
    int p = w*32 + nt*16 + l16;
    f4 aqk = z4;
    aqk = MFMA(a_qk[0], b_ys[nt][0], aqk);
    aqk = MFMA(a_qk[1], b_ys[nt][1], aqk);
    bf4 cv;
    #pragma unroll
    for (int rg = 0; rg < 4; ++rg) cv[rg] = (__bf16)aqk[rg];
    if (quad >= 2)
      *(bf4*)&ks[p*8 + (quad & 1)*4] = cv;
    bq[nt] = (quad < 2) ? cv : zb4;
  }
  __syncthreads();                      // B0b: all b_ys in regs; ys dead

  // ---- V proj SWAPPED into vs[64 d][140 c-pad] (aliases ys region) ----
  #pragma unroll
  for (int m0 = 0; m0 < 4; ++m0) {
    bf8 aw0 = *(const bf8*)&wtab[((2 + m0*2 + 0)*64 + lane)*8];
    bf8 aw1 = *(const bf8*)&wtab[((2 + m0*2 + 1)*64 + lane)*8];
    #pragma unroll
    for (int nt = 0; nt < 2; ++nt) {
      f4 va = z4;
      va = MFMA(b_ys[nt][0], aw0, va);
      va = MFMA(b_ys[nt][1], aw1, va);
      bf4 vv;
      #pragma unroll
      for (int rg = 0; rg < 4; ++rg) vv[rg] = (__bf16)va[rg];
      *(bf4*)&vs[(m0*16 + l16)*140 + w*32 + nt*16 + quad*4] = vv;
    }
  }
  __syncthreads();                      // B1: ks/vs visible

  // ---- tail: E^T = MFMA16(K,Q) -> exp2 -> UN-SWAPPED PV MFMA16(av,pb) ----
  // e[rg] = E[c=ct*16+quad*4+rg][p=w*32+nt*16+l16];  pb = B-frag P[c][p].
  // acc = MFMA16(av,pb): lane holds O[d=m0*16+quad*4+rg][p=w*32+nt*16+l16]
  // -> 4 CONSECUTIVE d per lane = pixel-major friendly.
  f4 acc[4][2];
  #pragma unroll
  for (int m0 = 0; m0 < 4; ++m0)
    #pragma unroll
    for (int nt = 0; nt < 2; ++nt) acc[m0][nt] = z4;
  float sm[2] = {0.f, 0.f};

  #pragma unroll
  for (int ct = 0; ct < 8; ++ct) {
    bf4 ak = (quad < 2) ? *(const bf4*)&ks[(ct*16 + l16)*8 + quad*4] : zb4;
    bf4 av[4];
    #pragma unroll
    for (int m0 = 0; m0 < 4; ++m0)
      av[m0] = *(const bf4*)&vs[(m0*16 + l16)*140 + ct*16 + quad*4];
    #pragma unroll
    for (int nt = 0; nt < 2; ++nt) {
      f4 e = MFMA16(ak, bq[nt], z4);
      if (dir) {                        // diag mask: c == p
        int pg = w*32 + nt*16 + l16, c0 = ct*16 + quad*4;
        #pragma unroll
        for (int rg = 0; rg < 4; ++rg)
          if (c0 + rg == pg) e[rg] = NEGINF;
      }
      bf4 pb;
      #pragma unroll
      for (int rg = 0; rg < 4; ++rg) {
        float pv = exp2f(e[rg]);        // wq pre-scaled by log2(e)
        sm[nt] += pv;
        pb[rg] = (__bf16)pv;
      }
      #pragma unroll
      for (int m0 = 0; m0 < 4; ++m0)
        acc[m0][nt] = MFMA16(av[m0], pb, acc[m0][nt]);
    }
  }

  // stats: lane holds partial S[p = nt*16+l16] over c; reduce quads
  int sb = ((b*128 + r) << 7);
  #pragma unroll
  for (int nt = 0; nt < 2; ++nt) {
    float s2 = sm[nt];
    s2 += __shfl_xor(s2, 16, 64);
    s2 += __shfl_xor(s2, 32, 64);
    if (quad == 0) so[sb + w*32 + nt*16 + l16] = s2;
  }
  __syncthreads();                      // B2: vs dead; region A reusable

  // out-stage per wave [32 p][70 d-pad]; then pixel-major global writes
  __bf16* oS = (__bf16*)(smem + 4480*w);
  #pragma unroll
  for (int m0 = 0; m0 < 4; ++m0)
    #pragma unroll
    for (int nt = 0; nt < 2; ++nt) {
      bf4 ov;
      #pragma unroll
      for (int rg = 0; rg < 4; ++rg) ov[rg] = (__bf16)acc[m0][nt][rg];
      *(bf4*)&oS[(nt*16 + l16)*70 + m0*16 + quad*4] = ov;
    }
  ushort* dp;
  size_t pstr;
  if (dir == 0) { dp = OW + ((size_t)b*128 + r)*8192; pstr = 64; }
  else          { dp = OH + (size_t)b*1048576 + (size_t)r*64; pstr = 8192; }
  ushort* oSu = (ushort*)oS;
  #pragma unroll
  for (int it = 0; it < 4; ++it) {
    int i = it*64 + lane;
    int pp = i >> 3, ch = i & 7;
    uint4 v = *(const uint4*)&oSu[pp*70 + ch*8];
    *(uint4*)&dp[(size_t)(w*32 + pp)*pstr + ch*8] = v;
  }
}

// Streaming elementwise combine:  dst(h,w,:) = g*(OW+OH)(h,w,:)*inv + res,
// inv = 1/(sW[b,h,w]+sH[b,w,h]).  Pixel-major everywhere; no LDS.
__global__ __launch_bounds__(256) void comb_kernel(
    ushort* __restrict__ dst, const ushort* __restrict__ OW,
    const ushort* __restrict__ OH, const ushort* __restrict__ res,
    const float* __restrict__ sW, const float* __restrict__ sH,
    const float* __restrict__ gamma) {
  int h = blockIdx.x, b = blockIdx.y;
  int t = threadIdx.x;
  int pix = t >> 1, half = t & 1;
  size_t base = ((size_t)b*128 + h)*8192 + (size_t)pix*64 + half*32;
  float g = *gamma;
  float inv = 1.0f/(sW[b*16384 + h*128 + pix] + sH[b*16384 + pix*128 + h]);
  float gi = g*inv;
  #pragma unroll
  for (int j = 0; j < 4; ++j) {
    uint4 uw = *(const uint4*)&OW[base + j*8];
    uint4 uh = *(const uint4*)&OH[base + j*8];
    uint4 ur = *(const uint4*)&res[base + j*8];
    const ushort* pw2 = (const ushort*)&uw;
    const ushort* ph2 = (const ushort*)&uh;
    const ushort* pr2 = (const ushort*)&ur;
    uint4 uo;
    ushort* po = (ushort*)&uo;
    #pragma unroll
    for (int k = 0; k < 8; ++k) {
      float v = fmaf(b2f(pw2[k]) + b2f(ph2[k]), gi, b2f(pr2[k]));
      po[k] = bfb(v);
    }
    *(uint4*)&dst[base + j*8] = uo;
  }
}

// MFMA pointwise 64->64: out[o][pix] = sum_c wpw[o][c]*A2(pix,c).
// A2 pixel-major (contiguous 16KB row-plane staging); SWAPPED MFMA ->
// p-major f4 stores into the FIXED out layout [b][o][h][w].
__global__ __launch_bounds__(256) void pw_kernel(
    const ushort* __restrict__ A2, const __bf16* __restrict__ ptab,
    float* __restrict__ out) {
  __shared__ __align__(16) char smem[18432];
  __bf16* ys = (__bf16*)smem;
  int t = threadIdx.x;
  int r = blockIdx.x, b = blockIdx.y;
  const ushort* base = A2 + ((size_t)b*128 + r)*8192;
  #pragma unroll
  for (int k = 0; k < 4; ++k) {                // 1024 chunks = full plane
    int i = t + 256*k;
    int p = i >> 3, c0 = (i & 7)*8;
    uint4 u = *(const uint4*)&base[(size_t)p*64 + c0];
    int cx = ((c0 >> 3) ^ (p >> 3)) & 7;
    *(uint4*)((ushort*)ys + p*72 + cx*8) = u;
  }
  int lane = t & 63, w = t >> 6;
  int l16 = lane & 15, quad = lane >> 4;
  __syncthreads();                     // ys staged
  bf8 b_ys[2][2];
  #pragma unroll
  for (int nt = 0; nt < 2; ++nt) {
    int p = w*32 + nt*16 + l16;
    int hi = (p >> 3) & 7;
    #pragma unroll
    for (int s = 0; s < 2; ++s)
      b_ys[nt][s] = *(const bf8*)&ys[p*72 + ((s*4 + quad) ^ hi)*8];
  }
  f4 z4 = {0.f, 0.f, 0.f, 0.f};
  float* dp = out + (size_t)b*1048576 + (size_t)r*128;
  #pragma unroll
  for (int m0 = 0; m0 < 4; ++m0) {
    bf8 aw0 = *(const bf8*)&ptab[((m0*2 + 0)*64 + lane)*8];
    bf8 aw1 = *(const bf8*)&ptab[((m0*2 + 1)*64 + lane)*8];
    #pragma unroll
    for (int nt = 0; nt < 2; ++nt) {
      f4 a2 = z4;
      a2 = MFMA(b_ys[nt][0], aw0, a2);
      a2 = MFMA(b_ys[nt][1], aw1, a2);
      *(f4*)&dp[(size_t)(m0*16 + l16)*16384 + w*32 + nt*16 + quad*4] = a2;
    }
  }
}

extern "C" void kernel_launch(void* const* d_in, const int* in_sizes, int n_in,
                              void* d_out, int out_size, void* d_ws, size_t ws_size,
                              hipStream_t stream) {
  const float* x     = (const float*)d_in[0];
  const float* wdw   = (const float*)d_in[1];
  const float* wq    = (const float*)d_in[2];
  const float* wk    = (const float*)d_in[3];
  const float* wv    = (const float*)d_in[4];
  const float* gamma = (const float*)d_in[5];
  const float* wpw   = (const float*)d_in[6];
  float* out = (float*)d_out;

  // Workspace: 6 bf16 buffers (16MB each) + tabs + 2 fp32 stat planes.
  __bf16* y_cp = (__bf16*)d_ws;            // dwconv out, channel-plane
  __bf16* yT_cp = y_cp + 8388608;          // dwconv transposed out
  ushort* yR2  = (ushort*)(yT_cp + 8388608);  // pixel-major y copy
  ushort* z    = yR2 + 8388608;            // pixel-major combined (pass0)
  ushort* OW   = z + 8388608;              // raw W-attention out
  ushort* OH   = OW + 8388608;             // raw H-attention out
  __bf16* wtab = (__bf16*)(OH + 8388608);  // 10 frags x 64 lanes x 8
  __bf16* ptab = wtab + 5120;              // 8 frags x 64 lanes x 8
  float* sW = (float*)(ptab + 4096);
  float* sH = sW + 131072;
  size_t need = (size_t)6*8388608*2 + (5120 + 4096)*2 + (size_t)2*131072*4;
  if (ws_size < need) return;

  dwconv_kernel<<<dim3(4, 4, 512), 256, 0, stream>>>(
      x, wdw, y_cp, yT_cp, wq, wk, wv, wpw, wtab, ptab);

  // pass 0: stage from channel-planes; emit yR2 residual copy
  ccdir_kernel<<<dim3(128, 8, 2), 256, 0, stream>>>(
      (const ushort*)y_cp, (const ushort*)yT_cp, OW, OH, yR2,
      wtab, sW, sH, 0);
  comb_kernel<<<dim3(128, 8), 256, 0, stream>>>(
      z, OW, OH, yR2, sW, sH, gamma);

  // pass 1: stage from pixel-major z (rows + cols)
  ccdir_kernel<<<dim3(128, 8, 2), 256, 0, stream>>>(
      z, z, OW, OH, yR2, wtab, sW, sH, 1);
  comb_kernel<<<dim3(128, 8), 256, 0, stream>>>(
      (ushort*)y_cp, OW, OH, z, sW, sH, gamma);   // y2 reuses y_cp buffer

  pw_kernel<<<dim3(128, 8), 256, 0, stream>>>(
      (const ushort*)y_cp, ptab, out);
}

// Round 14
// 189.748 us; speedup vs baseline: 1.0906x; 1.0906x over previous
//
#include <hip/hip_runtime.h>

// B=8, C=64, D=8 (q/k), H=W=128.  dwconv3x3 -> CCA -> CCA -> pointwise.
// Round 19.  r18 accounting: 450MB traffic / 206us = 2.2 TB/s effective ==
// what every visible kernel measures individually (2.4-3.5) => per-kernel
// BW inefficiency x traffic is the whole story.  This round: PASS FUSION
// (no grid barriers):
//   comb0 -> cc1 staging ("ccf"): stage z1 = g*(OW0+OH0)*inv + y on the
//     fly from 3 contiguous streams; dir0 also writes z1 plane (pass-2
//     residual).  comb1 -> pw staging ("pwf"): z2 lives only in LDS.
//   6 -> 4 dispatches; 451 -> ~405 MB.  OW1/OH1 reuse dead y_cp/yT_cp.
// All patterns + E/PV tail identical to r18 (proven).
// Fragment layouts (mfma_f32_16x16x32_bf16):
//   A[m=lane&15][k=quad*8+j (+32s)], B[k][n=lane&15], C col=lane&15,row=quad*4+reg
// (mfma_f32_16x16x16bf16_1k): A[m=lane&15][k=quad*4+j], B[k=quad*4+j][n=lane&15],
//   C col=lane&15,row=quad*4+reg.

#define NEGINF -3.0e38f

typedef __attribute__((ext_vector_type(8))) __bf16 bf8;
typedef __attribute__((ext_vector_type(4))) __bf16 bf4;
typedef __attribute__((ext_vector_type(4))) short s4;
typedef __attribute__((ext_vector_type(4))) float f4;

__device__ __forceinline__ f4 MFMA(bf8 a, bf8 b, f4 c) {
  return __builtin_amdgcn_mfma_f32_16x16x32_bf16(a, b, c, 0, 0, 0);
}
__device__ __forceinline__ f4 MFMA16(bf4 a, bf4 b, f4 c) {
  return __builtin_amdgcn_mfma_f32_16x16x16bf16_1k(*(s4*)&a, *(s4*)&b, c, 0, 0, 0);
}
__device__ __forceinline__ ushort bfb(float f) {
  __bf16 h = (__bf16)f;
  return *(ushort*)&h;
}
__device__ __forceinline__ float b2f(ushort u) {
  return (float)*(__bf16*)&u;
}

// 32x32-tile dwconv3x3; writes y_cp and yT_cp (channel-plane bf16).
// Block (0,0,0) lanes 0-63 also pack the weight-fragment tables.
__global__ __launch_bounds__(256) void dwconv_kernel(
    const float* __restrict__ x, const float* __restrict__ wdw,
    __bf16* __restrict__ y, __bf16* __restrict__ yT,
    const float* __restrict__ wq, const float* __restrict__ wk,
    const float* __restrict__ wv, const float* __restrict__ wpw,
    __bf16* __restrict__ wtab, __bf16* __restrict__ ptab) {
  __shared__ float in[34][36];
  __shared__ float ot[32][33];
  if (blockIdx.x == 0 && blockIdx.y == 0 && blockIdx.z == 0 &&
      threadIdx.x < 64) {
    int lane = threadIdx.x;
    int l16 = lane & 15, quad = lane >> 4;
    const float* wr = (l16 < 8) ? (wq + l16*64) : (wk + (l16 - 8)*64);
    float scale = (l16 < 8) ? 1.4426950408889634f : 1.0f;   // log2(e) on wq
    for (int s = 0; s < 2; ++s)
      for (int j = 0; j < 8; ++j)
        wtab[(s*64 + lane)*8 + j] = (__bf16)(wr[quad*8 + s*32 + j]*scale);
    for (int m0 = 0; m0 < 4; ++m0) {
      const float* vr = wv + (m0*16 + l16)*64;
      const float* pr = wpw + (m0*16 + l16)*64;
      for (int s = 0; s < 2; ++s)
        for (int j = 0; j < 8; ++j) {
          wtab[((2 + m0*2 + s)*64 + lane)*8 + j] = (__bf16)vr[quad*8 + s*32 + j];
          ptab[((m0*2 + s)*64 + lane)*8 + j]     = (__bf16)pr[quad*8 + s*32 + j];
        }
    }
  }
  int tx = threadIdx.x & 31, ty = threadIdx.x >> 5;   // 32x8
  int w0 = blockIdx.x*32, h0 = blockIdx.y*32;
  int n = blockIdx.z;                                  // b*64 + c
  const float* xp = x + (size_t)n*16384;
  const float* wp = wdw + (n & 63)*9;
  float wr[9];
  #pragma unroll
  for (int j = 0; j < 9; ++j) wr[j] = wp[j];
  for (int idx = threadIdx.x; idx < 1156; idx += 256) {  // 34*34 linear
    int i = idx/34, j = idx - i*34;
    int hh = h0 + i - 1, ww = w0 + j - 1;
    float v = 0.f;
    if (hh >= 0 && hh < 128 && ww >= 0 && ww < 128) v = xp[hh*128 + ww];
    in[i][j] = v;
  }
  __syncthreads();
  for (int i2 = ty; i2 < 32; i2 += 8) {
    float acc = 0.f;
    #pragma unroll
    for (int kh = 0; kh < 3; ++kh)
      #pragma unroll
      for (int kw = 0; kw < 3; ++kw)
        acc += wr[kh*3 + kw]*in[i2 + kh][tx + kw];
    ot[i2][tx] = acc;
  }
  __syncthreads();
  ushort* yp  = (ushort*)(y  + (size_t)n*16384);
  ushort* ytp = (ushort*)(yT + (size_t)n*16384);
  for (int idx = threadIdx.x; idx < 512; idx += 256) {
    int row = idx >> 4, c2 = (idx & 15)*2;
    ushort2 u;
    u.x = bfb(ot[row][c2]); u.y = bfb(ot[row][c2 + 1]);
    *(ushort2*)&yp[(size_t)(h0 + row)*128 + w0 + c2] = u;
    ushort2 v;
    v.x = bfb(ot[c2][row]); v.y = bfb(ot[c2 + 1][row]);
    *(ushort2*)&ytp[(size_t)(w0 + row)*128 + h0 + c2] = v;
  }
}

// Pass-0 CCA direction kernel (stages from channel-planes).  Outputs
// UNNORMALIZED, PIXEL-MAJOR:
//   dir0: OW(b, r, w=p, d) contiguous plane;  dir1: OH(b, h=p, r, d).
// dir0 also copies the staged plane to yR2 (pixel-major residual).
// LDS time-share: region A @0 (18432) = ys[128][72] -> vs[64][140] ->
// per-wave out-stage [32][70]; ks @18432 (2048).
__global__ __launch_bounds__(256) void ccdir_kernel(
    const ushort* __restrict__ srcA, const ushort* __restrict__ srcB,
    ushort* __restrict__ OW, ushort* __restrict__ OH,
    ushort* __restrict__ yR2,
    const __bf16* __restrict__ wtab,
    float* __restrict__ sW, float* __restrict__ sH) {
  __shared__ __align__(16) char smem[20480];
  __bf16* ys = (__bf16*)smem;
  __bf16* vs = (__bf16*)smem;                 // alias (post-B0b)
  __bf16* ks = (__bf16*)(smem + 18432);

  int t = threadIdx.x;
  int r = blockIdx.x, b = blockIdx.y, dir = blockIdx.z;
  float* so = dir ? sH : sW;

  int lane = t & 63, w = t >> 6;
  int l16 = lane & 15, quad = lane >> 4;

  // ---- stage Y[c][p] (channel-planes) -> ys[p][c-chunk-swizzled] ----
  {
    const ushort* sp = (dir ? srcB : srcA) + (size_t)b*1048576 + (size_t)r*128;
    int a = t & 15, cp = t >> 4;
    ushort* yr = (ushort*)ys;
    #pragma unroll
    for (int q = 0; q < 2; ++q) {
      int c = 2*cp + 32*q;
      uint4 u0 = *(const uint4*)&sp[(size_t)c*16384 + a*8];
      uint4 u1 = *(const uint4*)&sp[(size_t)(c + 1)*16384 + a*8];
      const ushort* p0 = (const ushort*)&u0;
      const ushort* p1 = (const ushort*)&u1;
      int cx = (((c >> 3) ^ a) & 7)*8 + (c & 7);
      #pragma unroll
      for (int j = 0; j < 8; ++j) {
        ushort2 uv; uv.x = p0[j]; uv.y = p1[j];
        *(ushort2*)&yr[(a*8 + j)*72 + cx] = uv;
      }
    }
  }
  bf8 a_qk[2];
  #pragma unroll
  for (int s = 0; s < 2; ++s)
    a_qk[s] = *(const bf8*)&wtab[(s*64 + lane)*8];
  __syncthreads();                      // B0: ys staged

  // ---- frag loads (+ yR2 copy on dir0) + QK proj ----
  f4 z4 = {0.f, 0.f, 0.f, 0.f};
  bf4 zb4;
  #pragma unroll
  for (int j = 0; j < 4; ++j) zb4[j] = (__bf16)0.f;
  bf8 b_ys[2][2];
  #pragma unroll
  for (int nt = 0; nt < 2; ++nt) {
    int p = w*32 + nt*16 + l16;
    int hi = (p >> 3) & 7;
    #pragma unroll
    for (int s = 0; s < 2; ++s)
      b_ys[nt][s] = *(const bf8*)&ys[p*72 + ((s*4 + quad) ^ hi)*8];
  }
  if (dir == 0) {                       // residual copy y -> yR2 (16KB plane)
    ushort* yp = yR2 + ((size_t)b*128 + r)*8192;
    #pragma unroll
    for (int k = 0; k < 4; ++k) {
      int i = t + 256*k;
      int pp = i >> 3, c0 = (i & 7)*8;
      int cx = ((c0 >> 3) ^ (pp >> 3)) & 7;
      uint4 v = *(const uint4*)((ushort*)ys + pp*72 + cx*8);
      *(uint4*)&yp[(size_t)pp*64 + c0] = v;
    }
  }
  // QK proj: C rows 0-7 = Q (quads 0,1) stay in regs; rows 8-15 = K -> ks.
  bf4 bq[2];
  #pragma unroll
  for (int nt = 0; nt < 2; ++nt) {
    int p = w*32 + nt*16 + l16;
    f4 aqk = z4;
    aqk = MFMA(a_qk[0], b_ys[nt][0], aqk);
    aqk = MFMA(a_qk[1], b_ys[nt][1], aqk);
    bf4 cv;
    #pragma unroll
    for (int rg = 0; rg < 4; ++rg) cv[rg] = (__bf16)aqk[rg];
    if (quad >= 2)
      *(bf4*)&ks[p*8 + (quad & 1)*4] = cv;
    bq[nt] = (quad < 2) ? cv : zb4;
  }
  __syncthreads();                      // B0b: all b_ys in regs; ys dead

  // ---- V proj SWAPPED into vs[64 d][140 c-pad] ----
  #pragma unroll
  for (int m0 = 0; m0 < 4; ++m0) {
    bf8 aw0 = *(const bf8*)&wtab[((2 + m0*2 + 0)*64 + lane)*8];
    bf8 aw1 = *(const bf8*)&wtab[((2 + m0*2 + 1)*64 + lane)*8];
    #pragma unroll
    for (int nt = 0; nt < 2; ++nt) {
      f4 va = z4;
      va = MFMA(b_ys[nt][0], aw0, va);
      va = MFMA(b_ys[nt][1], aw1, va);
      bf4 vv;
      #pragma unroll
      for (int rg = 0; rg < 4; ++rg) vv[rg] = (__bf16)va[rg];
      *(bf4*)&vs[(m0*16 + l16)*140 + w*32 + nt*16 + quad*4] = vv;
    }
  }
  __syncthreads();                      // B1: ks/vs visible

  // ---- tail: E^T = MFMA16(K,Q) -> exp2 -> PV MFMA16(av,pb) ----
  f4 acc[4][2];
  #pragma unroll
  for (int m0 = 0; m0 < 4; ++m0)
    #pragma unroll
    for (int nt = 0; nt < 2; ++nt) acc[m0][nt] = z4;
  float sm[2] = {0.f, 0.f};

  #pragma unroll
  for (int ct = 0; ct < 8; ++ct) {
    bf4 ak = (quad < 2) ? *(const bf4*)&ks[(ct*16 + l16)*8 + quad*4] : zb4;
    bf4 av[4];
    #pragma unroll
    for (int m0 = 0; m0 < 4; ++m0)
      av[m0] = *(const bf4*)&vs[(m0*16 + l16)*140 + ct*16 + quad*4];
    #pragma unroll
    for (int nt = 0; nt < 2; ++nt) {
      f4 e = MFMA16(ak, bq[nt], z4);
      if (dir) {                        // diag mask: c == p
        int pg = w*32 + nt*16 + l16, c0 = ct*16 + quad*4;
        #pragma unroll
        for (int rg = 0; rg < 4; ++rg)
          if (c0 + rg == pg) e[rg] = NEGINF;
      }
      bf4 pb;
      #pragma unroll
      for (int rg = 0; rg < 4; ++rg) {
        float pv = exp2f(e[rg]);        // wq pre-scaled by log2(e)
        sm[nt] += pv;
        pb[rg] = (__bf16)pv;
      }
      #pragma unroll
      for (int m0 = 0; m0 < 4; ++m0)
        acc[m0][nt] = MFMA16(av[m0], pb, acc[m0][nt]);
    }
  }

  // stats: lane holds partial S[p = nt*16+l16] over c; reduce quads
  int sb = ((b*128 + r) << 7);
  #pragma unroll
  for (int nt = 0; nt < 2; ++nt) {
    float s2 = sm[nt];
    s2 += __shfl_xor(s2, 16, 64);
    s2 += __shfl_xor(s2, 32, 64);
    if (quad == 0) so[sb + w*32 + nt*16 + l16] = s2;
  }
  __syncthreads();                      // B2: vs dead; region A reusable

  // out-stage per wave [32 p][70 d-pad]; pixel-major global writes
  __bf16* oS = (__bf16*)(smem + 4480*w);
  #pragma unroll
  for (int m0 = 0; m0 < 4; ++m0)
    #pragma unroll
    for (int nt = 0; nt < 2; ++nt) {
      bf4 ov;
      #pragma unroll
      for (int rg = 0; rg < 4; ++rg) ov[rg] = (__bf16)acc[m0][nt][rg];
      *(bf4*)&oS[(nt*16 + l16)*70 + m0*16 + quad*4] = ov;
    }
  ushort* dp;
  size_t pstr;
  if (dir == 0) { dp = OW + ((size_t)b*128 + r)*8192; pstr = 64; }
  else          { dp = OH + (size_t)b*1048576 + (size_t)r*64; pstr = 8192; }
  ushort* oSu = (ushort*)oS;
  #pragma unroll
  for (int it = 0; it < 4; ++it) {
    int i = it*64 + lane;
    int pp = i >> 3, ch = i & 7;
    uint4 v = *(const uint4*)&oSu[pp*70 + ch*8];
    *(uint4*)&dp[(size_t)(w*32 + pp)*pstr + ch*8] = v;
  }
}

// Pass-1 CCA with FUSED comb0 in the staging loop:
//   z1 = g*(OW0+OH0)*inv0 + yR2 computed on the fly (3 streams); dir0
//   blocks also write the z1 plane (pass-2 residual).  Tail identical.
__global__ __launch_bounds__(256) void ccf_kernel(
    const ushort* __restrict__ OW0, const ushort* __restrict__ OH0,
    const ushort* __restrict__ yR2, ushort* __restrict__ z1,
    ushort* __restrict__ OW1, ushort* __restrict__ OH1,
    const __bf16* __restrict__ wtab,
    const float* __restrict__ sW0, const float* __restrict__ sH0,
    float* __restrict__ sW1, float* __restrict__ sH1,
    const float* __restrict__ gamma) {
  __shared__ __align__(16) char smem[20480];
  __bf16* ys = (__bf16*)smem;
  __bf16* vs = (__bf16*)smem;                 // alias (post-B0b)
  __bf16* ks = (__bf16*)(smem + 18432);

  int t = threadIdx.x;
  int r = blockIdx.x, b = blockIdx.y, dir = blockIdx.z;
  float* so = dir ? sH1 : sW1;
  float g = *gamma;

  int lane = t & 63, w = t >> 6;
  int l16 = lane & 15, quad = lane >> 4;

  // ---- fused stage: z1[p][c] -> ys (+ z1 global on dir0) ----
  {
    size_t rowbase = ((size_t)b*128 + r)*8192;
    size_t colbase = (size_t)b*1048576 + (size_t)r*64;
    const float* swp = sW0 + b*16384;
    const float* shp = sH0 + b*16384;
    ushort* yr = (ushort*)ys;
    #pragma unroll
    for (int k = 0; k < 4; ++k) {
      int i = t + 256*k;
      int p = i >> 3, c0 = (i & 7)*8;
      size_t off = dir ? (colbase + (size_t)p*8192 + c0)
                       : (rowbase + (size_t)p*64 + c0);
      float inv = dir ? 1.0f/(swp[p*128 + r] + shp[r*128 + p])
                      : 1.0f/(swp[r*128 + p] + shp[p*128 + r]);
      float gi = g*inv;
      uint4 uw = *(const uint4*)&OW0[off];
      uint4 uh = *(const uint4*)&OH0[off];
      uint4 ur = *(const uint4*)&yR2[off];
      const ushort* pw2 = (const ushort*)&uw;
      const ushort* ph2 = (const ushort*)&uh;
      const ushort* pr2 = (const ushort*)&ur;
      uint4 uo;
      ushort* po = (ushort*)&uo;
      #pragma unroll
      for (int kk = 0; kk < 8; ++kk)
        po[kk] = bfb(fmaf(b2f(pw2[kk]) + b2f(ph2[kk]), gi, b2f(pr2[kk])));
      int cx = ((c0 >> 3) ^ (p >> 3)) & 7;
      *(uint4*)&yr[p*72 + cx*8] = uo;
      if (dir == 0)
        *(uint4*)&z1[rowbase + (size_t)p*64 + c0] = uo;
    }
  }
  bf8 a_qk[2];
  #pragma unroll
  for (int s = 0; s < 2; ++s)
    a_qk[s] = *(const bf8*)&wtab[(s*64 + lane)*8];
  __syncthreads();                      // B0: ys staged

  f4 z4 = {0.f, 0.f, 0.f, 0.f};
  bf4 zb4;
  #pragma unroll
  for (int j = 0; j < 4; ++j) zb4[j] = (__bf16)0.f;
  bf8 b_ys[2][2];
  #pragma unroll
  for (int nt = 0; nt < 2; ++nt) {
    int p = w*32 + nt*16 + l16;
    int hi = (p >> 3) & 7;
    #pragma unroll
    for (int s = 0; s < 2; ++s)
      b_ys[nt][s] = *(const bf8*)&ys[p*72 + ((s*4 + quad) ^ hi)*8];
  }
  bf4 bq[2];
  #pragma unroll
  for (int nt = 0; nt < 2; ++nt) {
    int p = w*32 + nt*16 + l16;
    f4 aqk = z4;
    aqk = MFMA(a_qk[0], b_ys[nt][0], aqk);
    aqk = MFMA(a_qk[1], b_ys[nt][1], aqk);
    bf4 cv;
    #pragma unroll
    for (int rg = 0; rg < 4; ++rg) cv[rg] = (__bf16)aqk[rg];
    if (quad >= 2)
      *(bf4*)&ks[p*8 + (quad & 1)*4] = cv;
    bq[nt] = (quad < 2) ? cv : zb4;
  }
  __syncthreads();                      // B0b

  #pragma unroll
  for (int m0 = 0; m0 < 4; ++m0) {
    bf8 aw0 = *(const bf8*)&wtab[((2 + m0*2 + 0)*64 + lane)*8];
    bf8 aw1 = *(const bf8*)&wtab[((2 + m0*2 + 1)*64 + lane)*8];
    #pragma unroll
    for (int nt = 0; nt < 2; ++nt) {
      f4 va = z4;
      va = MFMA(b_ys[nt][0], aw0, va);
      va = MFMA(b_ys[nt][1], aw1, va);
      bf4 vv;
      #pragma unroll
      for (int rg = 0; rg < 4; ++rg) vv[rg] = (__bf16)va[rg];
      *(bf4*)&vs[(m0*16 + l16)*140 + w*32 + nt*16 + quad*4] = vv;
    }
  }
  __syncthreads();                      // B1

  f4 acc[4][2];
  #pragma unroll
  for (int m0 = 0; m0 < 4; ++m0)
    #pragma unroll
    for (int nt = 0; nt < 2; ++nt) acc[m0][nt] = z4;
  float sm[2] = {0.f, 0.f};

  #pragma unroll
  for (int ct = 0; ct < 8; ++ct) {
    bf4 ak = (quad < 2) ? *(const bf4*)&ks[(ct*16 + l16)*8 + quad*4] : zb4;
    bf4 av[4];
    #pragma unroll
    for (int m0 = 0; m0 < 4; ++m0)
      av[m0] = *(const bf4*)&vs[(m0*16 + l16)*140 + ct*16 + quad*4];
    #pragma unroll
    for (int nt = 0; nt < 2; ++nt) {
      f4 e = MFMA16(ak, bq[nt], z4);
      if (dir) {
        int pg = w*32 + nt*16 + l16, c0 = ct*16 + quad*4;
        #pragma unroll
        for (int rg = 0; rg < 4; ++rg)
          if (c0 + rg == pg) e[rg] = NEGINF;
      }
      bf4 pb;
      #pragma unroll
      for (int rg = 0; rg < 4; ++rg) {
        float pv = exp2f(e[rg]);
        sm[nt] += pv;
        pb[rg] = (__bf16)pv;
      }
      #pragma unroll
      for (int m0 = 0; m0 < 4; ++m0)
        acc[m0][nt] = MFMA16(av[m0], pb, acc[m0][nt]);
    }
  }

  int sb = ((b*128 + r) << 7);
  #pragma unroll
  for (int nt = 0; nt < 2; ++nt) {
    float s2 = sm[nt];
    s2 += __shfl_xor(s2, 16, 64);
    s2 += __shfl_xor(s2, 32, 64);
    if (quad == 0) so[sb + w*32 + nt*16 + l16] = s2;
  }
  __syncthreads();                      // B2

  __bf16* oS = (__bf16*)(smem + 4480*w);
  #pragma unroll
  for (int m0 = 0; m0 < 4; ++m0)
    #pragma unroll
    for (int nt = 0; nt < 2; ++nt) {
      bf4 ov;
      #pragma unroll
      for (int rg = 0; rg < 4; ++rg) ov[rg] = (__bf16)acc[m0][nt][rg];
      *(bf4*)&oS[(nt*16 + l16)*70 + m0*16 + quad*4] = ov;
    }
  ushort* dp;
  size_t pstr;
  if (dir == 0) { dp = OW1 + ((size_t)b*128 + r)*8192; pstr = 64; }
  else          { dp = OH1 + (size_t)b*1048576 + (size_t)r*64; pstr = 8192; }
  ushort* oSu = (ushort*)oS;
  #pragma unroll
  for (int it = 0; it < 4; ++it) {
    int i = it*64 + lane;
    int pp = i >> 3, ch = i & 7;
    uint4 v = *(const uint4*)&oSu[pp*70 + ch*8];
    *(uint4*)&dp[(size_t)(w*32 + pp)*pstr + ch*8] = v;
  }
}

// Pointwise with FUSED comb1: stage z2 = g*(OW1+OH1)*inv1 + z1 row-wise
// into ys (never touches HBM), then MFMA; out fixed [b][o][h][w] fp32.
__global__ __launch_bounds__(256) void pwf_kernel(
    const ushort* __restrict__ OW1, const ushort* __restrict__ OH1,
    const ushort* __restrict__ z1,
    const float* __restrict__ sW1, const float* __restrict__ sH1,
    const float* __restrict__ gamma,
    const __bf16* __restrict__ ptab, float* __restrict__ out) {
  __shared__ __align__(16) char smem[18432];
  __bf16* ys = (__bf16*)smem;
  int t = threadIdx.x;
  int r = blockIdx.x, b = blockIdx.y;
  float g = *gamma;
  {
    size_t rowbase = ((size_t)b*128 + r)*8192;
    const float* swp = sW1 + b*16384;
    const float* shp = sH1 + b*16384;
    ushort* yr = (ushort*)ys;
    #pragma unroll
    for (int k = 0; k < 4; ++k) {
      int i = t + 256*k;
      int p = i >> 3, c0 = (i & 7)*8;
      size_t off = rowbase + (size_t)p*64 + c0;
      float inv = 1.0f/(swp[r*128 + p] + shp[p*128 + r]);
      float gi = g*inv;
      uint4 uw = *(const uint4*)&OW1[off];
      uint4 uh = *(const uint4*)&OH1[off];
      uint4 ur = *(const uint4*)&z1[off];
      const ushort* pw2 = (const ushort*)&uw;
      const ushort* ph2 = (const ushort*)&uh;
      const ushort* pr2 = (const ushort*)&ur;
      uint4 uo;
      ushort* po = (ushort*)&uo;
      #pragma unroll
      for (int kk = 0; kk < 8; ++kk)
        po[kk] = bfb(fmaf(b2f(pw2[kk]) + b2f(ph2[kk]), gi, b2f(pr2[kk])));
      int cx = ((c0 >> 3) ^ (p >> 3)) & 7;
      *(uint4*)&yr[p*72 + cx*8] = uo;
    }
  }
  int lane = t & 63, w = t >> 6;
  int l16 = lane & 15, quad = lane >> 4;
  __syncthreads();                     // ys staged
  bf8 b_ys[2][2];
  #pragma unroll
  for (int nt = 0; nt < 2; ++nt) {
    int p = w*32 + nt*16 + l16;
    int hi = (p >> 3) & 7;
    #pragma unroll
    for (int s = 0; s < 2; ++s)
      b_ys[nt][s] = *(const bf8*)&ys[p*72 + ((s*4 + quad) ^ hi)*8];
  }
  f4 z4 = {0.f, 0.f, 0.f, 0.f};
  float* dp = out + (size_t)b*1048576 + (size_t)r*128;
  #pragma unroll
  for (int m0 = 0; m0 < 4; ++m0) {
    bf8 aw0 = *(const bf8*)&ptab[((m0*2 + 0)*64 + lane)*8];
    bf8 aw1 = *(const bf8*)&ptab[((m0*2 + 1)*64 + lane)*8];
    #pragma unroll
    for (int nt = 0; nt < 2; ++nt) {
      f4 a2 = z4;
      a2 = MFMA(b_ys[nt][0], aw0, a2);
      a2 = MFMA(b_ys[nt][1], aw1, a2);
      *(f4*)&dp[(size_t)(m0*16 + l16)*16384 + w*32 + nt*16 + quad*4] = a2;
    }
  }
}

extern "C" void kernel_launch(void* const* d_in, const int* in_sizes, int n_in,
                              void* d_out, int out_size, void* d_ws, size_t ws_size,
                              hipStream_t stream) {
  const float* x     = (const float*)d_in[0];
  const float* wdw   = (const float*)d_in[1];
  const float* wq    = (const float*)d_in[2];
  const float* wk    = (const float*)d_in[3];
  const float* wv    = (const float*)d_in[4];
  const float* gamma = (const float*)d_in[5];
  const float* wpw   = (const float*)d_in[6];
  float* out = (float*)d_out;

  // Workspace: 6 bf16 buffers (16MB each) + tabs + 4 fp32 stat planes.
  __bf16* y_cp  = (__bf16*)d_ws;               // dwconv out / OW1 (reuse)
  __bf16* yT_cp = y_cp + 8388608;              // dwconv T out / OH1 (reuse)
  ushort* yR2   = (ushort*)(yT_cp + 8388608);  // pixel-major y copy
  ushort* z1    = yR2 + 8388608;               // pass-1 combined (pixel-major)
  ushort* OW    = z1 + 8388608;                // raw W-attention out (pass0)
  ushort* OH    = OW + 8388608;                // raw H-attention out (pass0)
  __bf16* wtab  = (__bf16*)(OH + 8388608);     // 10 frags x 64 lanes x 8
  __bf16* ptab  = wtab + 5120;                 // 8 frags x 64 lanes x 8
  float* sW0 = (float*)(ptab + 4096);
  float* sH0 = sW0 + 131072;
  float* sW1 = sH0 + 131072;
  float* sH1 = sW1 + 131072;
  size_t need = (size_t)6*8388608*2 + (5120 + 4096)*2 + (size_t)4*131072*4;
  if (ws_size < need) return;

  dwconv_kernel<<<dim3(4, 4, 512), 256, 0, stream>>>(
      x, wdw, y_cp, yT_cp, wq, wk, wv, wpw, wtab, ptab);

  // pass 0: stage from channel-planes; emit yR2 residual copy
  ccdir_kernel<<<dim3(128, 8, 2), 256, 0, stream>>>(
      (const ushort*)y_cp, (const ushort*)yT_cp, OW, OH, yR2,
      wtab, sW0, sH0);

  // pass 1 with fused comb0; OW1/OH1 reuse the dead y_cp/yT_cp buffers
  ccf_kernel<<<dim3(128, 8, 2), 256, 0, stream>>>(
      OW, OH, yR2, z1, (ushort*)y_cp, (ushort*)yT_cp,
      wtab, sW0, sH0, sW1, sH1, gamma);

  // pointwise with fused comb1
  pwf_kernel<<<dim3(128, 8), 256, 0, stream>>>(
      (const ushort*)y_cp, (const ushort*)yT_cp, z1, sW1, sH1, gamma,
      ptab, out);
}